// Round 3
// baseline (412.210 us; speedup 1.0000x reference)
//
#include <hip/hip_runtime.h>
#include <math.h>

#define HW   56
#define DIMC 256
#define HID  1024

typedef __attribute__((ext_vector_type(8))) short bf16x8;
typedef __attribute__((ext_vector_type(4))) float f32x4;

__device__ __forceinline__ short f2bf(float f) {
  union { float fv; unsigned u; } v; v.fv = f;
  unsigned r = v.u + 0x7fffu + ((v.u >> 16) & 1u);
  return (short)(r >> 16);
}
__device__ __forceinline__ float bf2f(short s) {
  union { unsigned u; float fv; } v; v.u = ((unsigned)(unsigned short)s) << 16;
  return v.fv;
}
// gelu via sigmoid: v*sigmoid(1.702v). rcp (1-ulp approx) fine: error scaled
// by gamma=1e-6 before reaching the output.
__device__ __forceinline__ float gelu_fast(float v) {
  float e = exp2f(-2.4556260f * v);
  return v * __builtin_amdgcn_rcpf(1.f + e);
}
// pack 8 f32 -> 8 OCP e4m3 bytes in one i64 (byte j = value j; A and B use the
// same j-indexing so any HW k-permutation within the 8-group cancels in MFMA).
__device__ __forceinline__ long pk8(float f0, float f1, float f2, float f3,
                                    float f4, float f5, float f6, float f7) {
  int lo = __builtin_amdgcn_cvt_pk_fp8_f32(f0, f1, 0, false);
  lo = __builtin_amdgcn_cvt_pk_fp8_f32(f2, f3, lo, true);
  int hi = __builtin_amdgcn_cvt_pk_fp8_f32(f4, f5, 0, false);
  hi = __builtin_amdgcn_cvt_pk_fp8_f32(f6, f7, hi, true);
  return ((long)(unsigned)lo) | ((long)hi << 32);
}
__device__ __forceinline__ char f2fp8(float f) {
  return (char)(__builtin_amdgcn_cvt_pk_fp8_f32(f, f, 0, false) & 0xff);
}

// ---------------------------------------------------------------------------
// prep_pack: weights -> fp8 MFMA-fragment-major (frag = 64 lanes x 8B = 512B).
//  w1p frag (ch*2+nh)*8+k8 : n=ch*32+nh*16+l15, k=k8*32+q*8+j, elem w1[k][n]
//  w2p frag ch*16+nt2      : k=ch*32+q*8+j, c=nt2*16+l15,      elem w2[k][c]
// ---------------------------------------------------------------------------
__global__ void prep_pack(const float* __restrict__ w1, const float* __restrict__ w2,
                          long* __restrict__ w1p, long* __restrict__ w2p) {
  int g = blockIdx.x * 256 + threadIdx.x;
  int f = g >> 6, lane = g & 63;
  int l15 = lane & 15, q = lane >> 4;
  float t[8];
  if (f < 512) {
    int k8 = f & 7, tt = f >> 3, nt = tt & 1, ch = tt >> 1;
    int n = ch * 32 + nt * 16 + l15;
    int k = k8 * 32 + q * 8;
    #pragma unroll
    for (int j = 0; j < 8; ++j) t[j] = w1[(k + j) * HID + n];
    w1p[f * 64 + lane] = pk8(t[0], t[1], t[2], t[3], t[4], t[5], t[6], t[7]);
  } else {
    int f2 = f - 512;
    int nt2 = f2 & 15, ch = f2 >> 4;
    int k = ch * 32 + q * 8;
    int c = nt2 * 16 + l15;
    #pragma unroll
    for (int j = 0; j < 8; ++j) t[j] = w2[(k + j) * DIMC + c];
    w2p[f2 * 64 + lane] = pk8(t[0], t[1], t[2], t[3], t[4], t[5], t[6], t[7]);
  }
}

// ---------------------------------------------------------------------------
// conv_k v2: depthwise 7x7 + bias, 16-channel groups (LDS 22400 B so multiple
// blocks/CU fit). Weights read per-thread from L1 (16 lanes share an address).
// s_yout aliases s_patch after a barrier. 16 threads per channel: wq 0..7 x
// h-half 0..1, 4 rows each.
// ---------------------------------------------------------------------------
__global__ __launch_bounds__(256, 4) void conv_k(
    const float* __restrict__ x, const int* __restrict__ mask,
    const float* __restrict__ dw_w, const float* __restrict__ dw_b,
    short* __restrict__ ybuf) {
  __shared__ __align__(16) float s_patch[16 * 14 * 20];   // 22400 B
  short* s_yout = (short*)s_patch;                        // alias (2048 B)

  int bid = blockIdx.x;
  int cgi = bid & 15; int t1 = bid >> 4;
  int wb = t1 % 7; int t2 = t1 / 7; int hb = t2 % 7; int b = t2 / 7;
  int tile = (b * 7 + hb) * 7 + wb;
  if (!mask[tile]) return;

  int tid = threadIdx.x;
  int h0 = hb * 8, w0 = wb * 8, cg0 = cgi * 16;

  // 16c x 14r x 4 vec-slots = 896 slots
  #pragma unroll
  for (int it = 0; it < 4; ++it) {
    int slot = tid + 256 * it;
    if (slot < 896) {
      int j = slot & 3, row = slot >> 2;      // row = c*14 + r
      int c = row / 14, r = row - c * 14;
      int gh = h0 - 3 + r;
      f32x4 v = (f32x4){0.f, 0.f, 0.f, 0.f};
      bool ok = (gh >= 0) && (gh < HW) && !(wb == 0 && j == 0) && !(wb == 6 && j == 3);
      if (ok)
        v = *(const f32x4*)(x + ((long)(b * DIMC + cg0 + c) * HW + gh) * HW + (w0 - 4) + 4 * j);
      *(f32x4*)(s_patch + c * 280 + r * 20 + 4 * j) = v;
    }
  }

  int cl = tid >> 4, s = tid & 15;
  int wq = s & 7, hf = s >> 3;                // 4 output rows: h = hf*4 + 0..3
  float wt[49];
  #pragma unroll
  for (int j = 0; j < 49; ++j) wt[j] = dw_w[(cg0 + cl) * 49 + j];
  __syncthreads();

  float y[4] = {0.f, 0.f, 0.f, 0.f};
  #pragma unroll
  for (int rr = 0; rr < 10; ++rr) {           // rows hf*4 .. hf*4+9
    float row[7];
    #pragma unroll
    for (int j = 0; j < 7; ++j) row[j] = s_patch[cl * 280 + (hf * 4 + rr) * 20 + wq + 1 + j];
    #pragma unroll
    for (int dy = 0; dy < 7; ++dy) {
      int hh = rr - dy;
      if (hh >= 0 && hh < 4) {
        #pragma unroll
        for (int dx = 0; dx < 7; ++dx) y[hh] += row[dx] * wt[dy * 7 + dx];
      }
    }
  }
  float db = dw_b[cg0 + cl];
  __syncthreads();                            // all patch reads done (alias!)
  #pragma unroll
  for (int hh = 0; hh < 4; ++hh)
    s_yout[cl * 64 + (hf * 4 + hh) * 8 + wq] = f2bf(y[hh] + db);
  __syncthreads();

  if (tid < 128) {
    int c = tid >> 3, pd = (tid & 7) * 8;
    bf16x8 v = *(const bf16x8*)(s_yout + c * 64 + pd);
    *(bf16x8*)(ybuf + ((long)tile * DIMC + cg0 + c) * 64 + pd) = v;
  }
}

// ---------------------------------------------------------------------------
// mlp_k v5: LDS 46592 -> 28160 B to raise residency (R1 counters: occupancy
// 16% ~= 1.3 blocks/CU => LDS-footprint-bound). The bf16 staging buffer is
// gone: the [c][p]->[p][c] transpose is done by coalesced u16 global reads
// (64 lanes on consecutive p = 128B lines), two passes (stats, normalize),
// LN'd A written straight to LDS as fp8 [64][280]. Delta epilogue stored fp8
// with gamma deferred to epi_k (s_del 36864 -> 18432 B).
// LDS: s_a8/s_del8 18432 | h(fp8 dbuf) 5120 | stats 4608 = 28160.
// ---------------------------------------------------------------------------
__global__ __launch_bounds__(256, 4) void mlp_k(
    const int* __restrict__ mask,
    const float* __restrict__ ln_w, const float* __restrict__ ln_b,
    const float* __restrict__ b1v, const float* __restrict__ b2v,
    const long* __restrict__ w1p, const long* __restrict__ w2p,
    short* __restrict__ ybuf) {
  __shared__ __align__(16) char smem[28160];
  char*  s_a8  = smem;                          // [p 64][280] fp8 (LN'd A)
  char*  s_del8 = smem;                         // alias: [c 256][72] fp8
  char*  s_h8  = smem + 18432;                  // 2 x [64 m][40] fp8
  float* s_p1  = (float*)(smem + 23552);
  float* s_p2  = (float*)(smem + 24576);
  float* s_mu  = (float*)(smem + 25600);
  float* s_rs  = (float*)(smem + 25856);
  float* s_lnw = (float*)(smem + 26112);
  float* s_lnb = (float*)(smem + 27136);

  int tile = blockIdx.x;
  if (!mask[tile]) return;
  int tid = threadIdx.x;
  const unsigned short* ytile = (const unsigned short*)(ybuf + (long)tile * DIMC * 64);

  s_lnw[tid] = ln_w[tid];
  s_lnb[tid] = ln_b[tid];

  // pass 1: LN stats. thread (p, cq) reads its 64 channels via coalesced u16
  // loads (lane index == p => consecutive addresses within the wave).
  int p = tid & 63, cq = tid >> 6;
  {
    float s1 = 0.f, s2 = 0.f;
    #pragma unroll 8
    for (int i = 0; i < 64; ++i) {
      float f = bf2f((short)ytile[(cq * 64 + i) * 64 + p]);
      s1 += f; s2 += f * f;
    }
    s_p1[cq * 64 + p] = s1; s_p2[cq * 64 + p] = s2;
  }
  __syncthreads();
  if (tid < 64) {
    float t1 = s_p1[tid] + s_p1[64 + tid] + s_p1[128 + tid] + s_p1[192 + tid];
    float t2 = s_p2[tid] + s_p2[64 + tid] + s_p2[128 + tid] + s_p2[192 + tid];
    float mu = t1 * (1.f / 256.f);
    float var = t2 * (1.f / 256.f) - mu * mu;
    s_mu[tid] = mu; s_rs[tid] = rsqrtf(var + 1e-6f);
  }
  __syncthreads();
  // pass 2: re-read (L1/L2-hot), normalize in f32, pack fp8 into s_a8.
  {
    float mu = s_mu[p], rs = s_rs[p];
    #pragma unroll
    for (int i = 0; i < 8; ++i) {
      int c0 = cq * 64 + i * 8;
      float f[8];
      #pragma unroll
      for (int j = 0; j < 8; ++j) {
        float v = bf2f((short)ytile[(c0 + j) * 64 + p]);
        f[j] = (v - mu) * rs * s_lnw[c0 + j] + s_lnb[c0 + j];
      }
      *(long*)(s_a8 + p * 280 + c0) = pk8(f[0], f[1], f[2], f[3], f[4], f[5], f[6], f[7]);
    }
  }
  __syncthreads();

  const int wv = tid >> 6, lane = tid & 63;
  const int l15 = lane & 15, q = lane >> 4;
  const int mh = wv & 1, nh = wv >> 1;          // GEMM1: 2M x 2N wave split

  // hoist the loop-invariant GEMM1 A-operand into fp8 registers (32 VGPRs)
  long a0f[8], a1f[8];
  #pragma unroll
  for (int k8 = 0; k8 < 8; ++k8) {
    a0f[k8] = *(const long*)(s_a8 + (32 * mh + l15) * 280 + k8 * 32 + q * 8);
    a1f[k8] = *(const long*)(s_a8 + (32 * mh + 16 + l15) * 280 + k8 * 32 + q * 8);
  }

  f32x4 z[4][4];                                // [jt][Mt], c = wv*64+jt*16+l15
  #pragma unroll
  for (int jt = 0; jt < 4; ++jt)
    #pragma unroll
    for (int Mt = 0; Mt < 4; ++Mt) z[jt][Mt] = (f32x4){0.f, 0.f, 0.f, 0.f};

  long w1r[8];                                  // prefetched W1 frags (ch=0)
  #pragma unroll
  for (int k8 = 0; k8 < 8; ++k8)
    w1r[k8] = w1p[(long)(nh * 8 + k8) * 64 + lane];

  for (int ch = 0; ch < 32; ++ch) {
    // issue W2 frags + bias now; consumed after barrier / after GEMM1
    long w2r[4];
    #pragma unroll
    for (int jt = 0; jt < 4; ++jt)
      w2r[jt] = w2p[(long)(ch * 16 + wv * 4 + jt) * 64 + lane];
    float bb = b1v[ch * 32 + 16 * nh + l15];

    f32x4 acc0 = (f32x4){0.f, 0.f, 0.f, 0.f};
    f32x4 acc1 = (f32x4){0.f, 0.f, 0.f, 0.f};
    __builtin_amdgcn_s_setprio(1);
    #pragma unroll
    for (int k8 = 0; k8 < 8; ++k8) {
      acc0 = __builtin_amdgcn_mfma_f32_16x16x32_fp8_fp8(a0f[k8], w1r[k8], acc0, 0, 0, 0);
      acc1 = __builtin_amdgcn_mfma_f32_16x16x32_fp8_fp8(a1f[k8], w1r[k8], acc1, 0, 0, 0);
    }
    __builtin_amdgcn_s_setprio(0);
    long w1n[8];                                // prefetch next chunk's W1
    if (ch < 31) {
      #pragma unroll
      for (int k8 = 0; k8 < 8; ++k8)
        w1n[k8] = w1p[(long)(((ch + 1) * 2 + nh) * 8 + k8) * 64 + lane];
    }
    char* hb = s_h8 + (ch & 1) * 2560;
    #pragma unroll
    for (int r = 0; r < 4; ++r) {
      hb[(32 * mh + 4 * q + r) * 40 + 16 * nh + l15]      = f2fp8(gelu_fast(acc0[r] + bb));
      hb[(32 * mh + 16 + 4 * q + r) * 40 + 16 * nh + l15] = f2fp8(gelu_fast(acc1[r] + bb));
    }
    __syncthreads();                            // h[ch&1] complete
    __builtin_amdgcn_s_setprio(1);
    #pragma unroll
    for (int Mt = 0; Mt < 4; ++Mt) {
      long aH = *(const long*)(hb + (16 * Mt + l15) * 40 + q * 8);
      #pragma unroll
      for (int jt = 0; jt < 4; ++jt)
        z[jt][Mt] = __builtin_amdgcn_mfma_f32_16x16x32_fp8_fp8(aH, w2r[jt], z[jt][Mt], 0, 0, 0);
    }
    __builtin_amdgcn_s_setprio(0);
    if (ch < 31) {
      #pragma unroll
      for (int k8 = 0; k8 < 8; ++k8) w1r[k8] = w1n[k8];
    }
  }

  // epilogue: store (z+b2) as fp8 (gamma applied in epi_k) -> s_del8 [c][72]
  // -> first 16KB of the tile's ybuf slot.
  #pragma unroll
  for (int jt = 0; jt < 4; ++jt) {
    int c = wv * 64 + jt * 16 + l15;
    float bb = b2v[c];
    #pragma unroll
    for (int Mt = 0; Mt < 4; ++Mt) {
      #pragma unroll
      for (int r = 0; r < 4; ++r)
        s_del8[c * 72 + 16 * Mt + 4 * q + r] = f2fp8(z[jt][Mt][r] + bb);
    }
  }
  __syncthreads();
  char* dtile8 = (char*)(ybuf + (long)tile * DIMC * 64);
  #pragma unroll
  for (int k = 0; k < 8; ++k) {
    int q4 = tid + 256 * k;
    int c = q4 & 255, pd = (q4 >> 8) * 8;
    long v = *(const long*)(s_del8 + c * 72 + pd);
    *(long*)(dtile8 + c * 64 + pd) = v;
  }
}

// ---------------------------------------------------------------------------
// epi_k: dense, fully coalesced. out = x + (active ? gamma_c * fp8(delta) : 0).
// ---------------------------------------------------------------------------
__global__ __launch_bounds__(256) void epi_k(
    const float* __restrict__ x, const int* __restrict__ mask,
    const short* __restrict__ delta, const float* __restrict__ gammav,
    float* __restrict__ out) {
  const char* delta8 = (const char*)delta;
  const int NU = 32 * DIMC * HW * 7;            // units of 8 floats
  int stride = gridDim.x * 256;
  for (int u = blockIdx.x * 256 + threadIdx.x; u < NU; u += stride) {
    int wb = u % 7; int t1 = u / 7;
    int h = t1 % 56; int t2 = t1 / 56;
    int c = t2 & 255; int b = t2 >> 8;
    int g = ((b * DIMC + c) * HW + h) * HW + wb * 8;
    f32x4 x0 = *(const f32x4*)(x + g);
    f32x4 x1 = *(const f32x4*)(x + g + 4);
    int tile = (b * 7 + (h >> 3)) * 7 + wb;
    if (mask[tile]) {
      long dl = *(const long*)(delta8 + (long)tile * 32768 + c * 64 + (h & 7) * 8);
      int lo = (int)(unsigned)dl, hi = (int)((unsigned long)dl >> 32);
      float gm = gammav[c];
      x0[0] += gm * __builtin_amdgcn_cvt_f32_fp8(lo, 0);
      x0[1] += gm * __builtin_amdgcn_cvt_f32_fp8(lo, 1);
      x0[2] += gm * __builtin_amdgcn_cvt_f32_fp8(lo, 2);
      x0[3] += gm * __builtin_amdgcn_cvt_f32_fp8(lo, 3);
      x1[0] += gm * __builtin_amdgcn_cvt_f32_fp8(hi, 0);
      x1[1] += gm * __builtin_amdgcn_cvt_f32_fp8(hi, 1);
      x1[2] += gm * __builtin_amdgcn_cvt_f32_fp8(hi, 2);
      x1[3] += gm * __builtin_amdgcn_cvt_f32_fp8(hi, 3);
    }
    *(f32x4*)(out + g) = x0;
    *(f32x4*)(out + g + 4) = x1;
  }
}

extern "C" void kernel_launch(void* const* d_in, const int* in_sizes, int n_in,
                              void* d_out, int out_size, void* d_ws, size_t ws_size,
                              hipStream_t stream) {
  const float* x    = (const float*)d_in[0];
  const int*   mask = (const int*)d_in[1];
  const float* dw_w = (const float*)d_in[2];
  const float* dw_b = (const float*)d_in[3];
  const float* ln_w = (const float*)d_in[4];
  const float* ln_b = (const float*)d_in[5];
  const float* w1   = (const float*)d_in[6];
  const float* b1   = (const float*)d_in[7];
  const float* w2   = (const float*)d_in[8];
  const float* b2   = (const float*)d_in[9];
  const float* gm   = (const float*)d_in[10];
  float* out = (float*)d_out;

  long* w1p  = (long*)d_ws;                     // 256 KB (512 frags x 512B)
  long* w2p  = w1p + 512 * 64;                  // 256 KB
  short* ybuf = (short*)(w2p + 512 * 64);       // 51.4 MB

  prep_pack<<<256, 256, 0, stream>>>(w1, w2, w1p, w2p);
  conv_k<<<25088, 256, 0, stream>>>(x, mask, dw_w, dw_b, ybuf);
  mlp_k<<<1568, 256, 0, stream>>>(mask, ln_w, ln_b, b1, b2, w1p, w2p, ybuf);
  epi_k<<<4096, 256, 0, stream>>>(x, mask, ybuf, gm, out);
}